// Round 6
// baseline (1887.137 us; speedup 1.0000x reference)
//
#include <hip/hip_runtime.h>
#include <hip/hip_fp16.h>
#include <math.h>

#define NN 100000
#define NR 8
#define NE 640000
#define SEGN (NN * NR)                 // 800000
#define SPB 2048                       // segments per scan block
#define NSB ((SEGN + SPB - 1) / SPB)   // 391

typedef __attribute__((ext_vector_type(8))) __bf16 bf16x8;
typedef __attribute__((ext_vector_type(4))) float  f32x4;
typedef unsigned long long u64;

__device__ __forceinline__ float bf2f(unsigned short b) {
    return __uint_as_float((unsigned)b << 16);
}
__device__ __forceinline__ unsigned short f2bf(float v) {
    __bf16 b = (__bf16)v;
    return __builtin_bit_cast(unsigned short, b);
}

// ---------------- preprocessing: CSR by (rel, dst) ----------------
// seg = rel * NN + dst  -> edges of a node-tile for fixed rel are CONTIGUOUS.

__global__ __launch_bounds__(256) void count_kernel(
    const int* __restrict__ dst, const int* __restrict__ et, unsigned* __restrict__ cnt) {
    int e = blockIdx.x * 256 + threadIdx.x;
    if (e < NE) atomicAdd(&cnt[(size_t)et[e] * NN + dst[e]], 1u);
}

__global__ __launch_bounds__(256) void scan1_kernel(
    const unsigned* __restrict__ cnt, unsigned* __restrict__ bsum) {
    __shared__ unsigned red[256];
    int b = blockIdx.x, t = threadIdx.x;
    int i0 = b * SPB;
    unsigned s = 0;
#pragma unroll
    for (int k = 0; k < SPB / 256; ++k) {
        int i = i0 + k * 256 + t;
        if (i < SEGN) s += cnt[i];
    }
    red[t] = s;
    __syncthreads();
    for (int off = 128; off >= 1; off >>= 1) {
        if (t < off) red[t] += red[t + off];
        __syncthreads();
    }
    if (t == 0) bsum[b] = red[0];
}

__global__ __launch_bounds__(512) void scan2_kernel(
    unsigned* __restrict__ bsum, int* __restrict__ segoff) {
    __shared__ unsigned buf[512];
    int t = threadIdx.x;
    unsigned v = (t < NSB) ? bsum[t] : 0u;
    buf[t] = v;
    __syncthreads();
    for (int off = 1; off < 512; off <<= 1) {
        unsigned w = (t >= off) ? buf[t - off] : 0u;
        __syncthreads();
        buf[t] += w;
        __syncthreads();
    }
    if (t < NSB) bsum[t] = buf[t] - v;   // exclusive block offsets
    if (t == 0) segoff[SEGN] = NE;
}

__global__ __launch_bounds__(256) void scan3_kernel(
    const unsigned* __restrict__ cnt, const unsigned* __restrict__ bsum,
    int* __restrict__ segoff) {
    __shared__ unsigned lc[SPB];
    __shared__ unsigned tsum[256];
    int b = blockIdx.x, t = threadIdx.x;
    int i0 = b * SPB;
#pragma unroll
    for (int k = 0; k < SPB / 256; ++k) {
        int i = i0 + k * 256 + t;
        lc[k * 256 + t] = (i < SEGN) ? cnt[i] : 0u;
    }
    __syncthreads();
    unsigned s = 0;
#pragma unroll
    for (int k = 0; k < 8; ++k) s += lc[t * 8 + k];
    tsum[t] = s;
    __syncthreads();
    for (int off = 1; off < 256; off <<= 1) {
        unsigned w = (t >= off) ? tsum[t - off] : 0u;
        __syncthreads();
        tsum[t] += w;
        __syncthreads();
    }
    unsigned base = bsum[b] + tsum[t] - s;
#pragma unroll
    for (int k = 0; k < 8; ++k) {
        unsigned c = lc[t * 8 + k];
        lc[t * 8 + k] = base;
        base += c;
    }
    __syncthreads();
#pragma unroll
    for (int k = 0; k < SPB / 256; ++k) {
        int i = i0 + k * 256 + t;
        if (i < SEGN) segoff[i] = (int)lc[k * 256 + t];
    }
}

// packed edge meta: bits [0,20)=src, [20,40)=dst, [40,56)=inv_cnt as f16
__global__ __launch_bounds__(256) void fill_kernel(
    const int* __restrict__ src, const int* __restrict__ dst, const int* __restrict__ et,
    const int* __restrict__ segoff, unsigned* __restrict__ cursor,
    const unsigned* __restrict__ cnt, u64* __restrict__ emeta) {
    int e = blockIdx.x * 256 + threadIdx.x;
    if (e >= NE) return;
    int d = dst[e];
    int seg = et[e] * NN + d;
    int pos = segoff[seg] + (int)atomicAdd(&cursor[seg], 1u);
    float invc = 1.0f / (float)cnt[seg];
    unsigned short h = __half_as_ushort(__float2half(invc));
    emeta[pos] = (u64)(unsigned)src[e] | ((u64)(unsigned)d << 20) | ((u64)h << 40);
}

// ---------------- weight pack: f32 -> bf16 in MFMA B-fragment order -------
// Wp block for (r,kt,nt): 64 lanes x 8 bf16.  Lane l holds
// B[k = kt*32 + (l>>4)*8 + j][n = nt*16 + (l&15)], j=0..7.

template <int D, int O>
__global__ __launch_bounds__(256) void pack_kernel(
    const float* __restrict__ W, const float* __restrict__ Wr, __bf16* __restrict__ Wp) {
    constexpr int KT = D / 32, NTN = O / 16;
    int idx = blockIdx.x * 256 + threadIdx.x;
    if (idx >= (NR + 1) * KT * NTN * 64) return;
    int l = idx & 63;
    int rest = idx >> 6;
    int nt = rest % NTN; rest /= NTN;
    int kt = rest % KT;
    int r  = rest / KT;
    const float* srcw = (r < NR) ? (W + (size_t)r * D * O) : Wr;
    int n  = nt * 16 + (l & 15);
    int k0 = kt * 32 + (l >> 4) * 8;
    bf16x8 v;
#pragma unroll
    for (int j = 0; j < 8; ++j) v[j] = (__bf16)srcw[(size_t)(k0 + j) * O + n];
    *(bf16x8*)(Wp + (size_t)idx * 8) = v;
}

// ---------------- fused layer: pipelined gather + 9-way MFMA GEMM + epilogue --
// XF (input fmt):  0 = f32 rows [D]   1 = bf16 pair-swizzled ushort2[64] (D=128)
//                  2 = bf16 plain ushort[64] (D=64)
// OF (output fmt): 0 = f32 rows [O]   1 = bf16 pair-swizzled (O=128)
//                  2 = bf16 plain (O=64)
// MODE 0: relu+LN; 1: relu+resid+LN; 2: relu; 3: plain

template <int D, int O, int MODE, int XF, int OF>
__global__ __launch_bounds__(256) void fused_layer(
    const void* __restrict__ xin, const __bf16* __restrict__ Wp,
    const float* __restrict__ bias, const float* __restrict__ gamma,
    const float* __restrict__ beta, const int* __restrict__ segoff,
    const u64* __restrict__ emeta, void* __restrict__ outv)
{
    constexpr int NT = 64, PADC = 65;
    constexpr int KT = D / 32, NTN = O / 16;

    __shared__ float saggT[D][PADC];   // dim-major agg tile (f32)

    int t  = threadIdx.x;
    int wv = t >> 6, ln = t & 63;
    int lg = ln >> 4, lm = ln & 15;
    int n0 = blockIdx.x * NT;
    int nclamp = (NN - n0 < NT) ? (NN - n0) : NT;

    const float*   xf = (const float*)xin;
    const ushort*  xb = (const ushort*)xin;
    const ushort2* xs = (const ushort2*)xin;

    f32x4 acc[NTN];
#pragma unroll
    for (int nt = 0; nt < NTN; ++nt)
#pragma unroll
        for (int q = 0; q < 4; ++q) acc[nt][q] = 0.0f;

    for (int r = 0; r <= NR; ++r) {
        int e0 = 0, e1 = 0;
        if (r < NR) {
            int segbase = r * NN + n0;
            e0 = segoff[segbase];
            e1 = segoff[segbase + nclamp];
            if (e0 == e1) continue;            // uniform across block
        }
        __syncthreads();                        // prev MFMA done reading saggT
        if (r < NR) {
            for (int idx = t; idx < D * PADC; idx += 256) (&saggT[0][0])[idx] = 0.0f;
            __syncthreads();
            // ---- 4-edge batched, meta-prefetching gather pipeline ----
            int base = e0 + wv * 4;
            u64 m[4];
#pragma unroll
            for (int k = 0; k < 4; ++k) m[k] = (base + k < e1) ? emeta[base + k] : 0ULL;
            while (base < e1) {
                int nb = base + 16;
                u64 nm[4];
#pragma unroll
                for (int k = 0; k < 4; ++k) nm[k] = (nb + k < e1) ? emeta[nb + k] : 0ULL;
                int cb = e1 - base; if (cb > 4) cb = 4;
                float vx[4], vy[4], cc[4]; int jj[4];
#pragma unroll
                for (int k = 0; k < 4; ++k) {
                    if (k < cb) {
                        int s = (int)(m[k] & 0xFFFFFu);
                        jj[k] = (int)((m[k] >> 20) & 0xFFFFFu) - n0;
                        cc[k] = __half2float(__ushort_as_half((unsigned short)(m[k] >> 40)));
                        if constexpr (XF == 0) {
                            vx[k] = xf[(size_t)s * D + ln];
                            if constexpr (D == 128) vy[k] = xf[(size_t)s * D + 64 + ln];
                        } else if constexpr (XF == 1) {
                            ushort2 w = xs[(size_t)s * 64 + ln];
                            vx[k] = bf2f(w.x);
                            vy[k] = bf2f(w.y);
                        } else {
                            vx[k] = bf2f(xb[(size_t)s * 64 + ln]);
                        }
                    }
                }
#pragma unroll
                for (int k = 0; k < 4; ++k) {
                    if (k < cb) {
                        atomicAdd(&saggT[ln][jj[k]], vx[k] * cc[k]);
                        if constexpr (D == 128) atomicAdd(&saggT[ln + 64][jj[k]], vy[k] * cc[k]);
                    }
                }
                base = nb;
#pragma unroll
                for (int k = 0; k < 4; ++k) m[k] = nm[k];
            }
        } else {
            // root: direct tile load
            for (int j = wv; j < nclamp; j += 4) {
                if constexpr (XF == 0) {
                    saggT[ln][j] = xf[(size_t)(n0 + j) * D + ln];
                    if constexpr (D == 128) saggT[ln + 64][j] = xf[(size_t)(n0 + j) * D + 64 + ln];
                } else if constexpr (XF == 1) {
                    ushort2 w = xs[(size_t)(n0 + j) * 64 + ln];
                    saggT[ln][j]      = bf2f(w.x);
                    saggT[ln + 64][j] = bf2f(w.y);
                } else {
                    saggT[ln][j] = bf2f(xb[(size_t)(n0 + j) * 64 + ln]);
                }
            }
        }
        __syncthreads();                        // saggT ready

        // ---- MFMA phase: wave wv computes rows [wv*16, wv*16+16) ----
#pragma unroll
        for (int kt = 0; kt < KT; ++kt) {
            bf16x8 A;
#pragma unroll
            for (int j = 0; j < 8; ++j)
                A[j] = (__bf16)saggT[kt * 32 + lg * 8 + j][wv * 16 + lm];
            const __bf16* bp = Wp + ((size_t)((r * KT + kt) * NTN) << 9) + (ln << 3);
#pragma unroll
            for (int nt = 0; nt < NTN; ++nt) {
                bf16x8 B = *(const bf16x8*)(bp + ((size_t)nt << 9));
                acc[nt] = __builtin_amdgcn_mfma_f32_16x16x32_bf16(A, B, acc[nt], 0, 0, 0);
            }
        }
    }

    // ---- epilogue (C/D layout: col = nt*16+lm, row = wv*16+lg*4+q) ----
    float bb[NTN], gg[NTN], be[NTN];
#pragma unroll
    for (int nt = 0; nt < NTN; ++nt) {
        bb[nt] = bias[nt * 16 + lm];
        if constexpr (MODE <= 1) {
            gg[nt] = gamma[nt * 16 + lm];
            be[nt] = beta[nt * 16 + lm];
        } else {
            gg[nt] = 0.0f; be[nt] = 0.0f;
        }
    }
#pragma unroll
    for (int q = 0; q < 4; ++q) {
        int row = wv * 16 + lg * 4 + q;
        int n = n0 + row;
        float v[NTN];
#pragma unroll
        for (int nt = 0; nt < NTN; ++nt) {
            v[nt] = acc[nt][q] + bb[nt];
            if constexpr (MODE <= 2) v[nt] = fmaxf(v[nt], 0.0f);
            if constexpr (MODE == 1) v[nt] += saggT[nt * 16 + lm][row];  // residual (root tile)
        }
        if constexpr (MODE <= 1) {
            float s1 = 0.0f, s2 = 0.0f;
#pragma unroll
            for (int nt = 0; nt < NTN; ++nt) { s1 += v[nt]; s2 += v[nt] * v[nt]; }
#pragma unroll
            for (int off = 1; off < 16; off <<= 1) {
                s1 += __shfl_xor(s1, off, 64);
                s2 += __shfl_xor(s2, off, 64);
            }
            float mu  = s1 * (1.0f / O);
            float var = s2 * (1.0f / O) - mu * mu;
            float rs  = rsqrtf(var + 1e-5f);
#pragma unroll
            for (int nt = 0; nt < NTN; ++nt) v[nt] = (v[nt] - mu) * rs * gg[nt] + be[nt];
        }
        if (n < NN) {
            if constexpr (OF == 0) {
#pragma unroll
                for (int nt = 0; nt < NTN; ++nt)
                    ((float*)outv)[(size_t)n * O + nt * 16 + lm] = v[nt];
            } else if constexpr (OF == 1) {          // O=128 pair-swizzled bf16
#pragma unroll
                for (int nt = 0; nt < 4; ++nt)
                    ((ushort2*)outv)[(size_t)n * 64 + nt * 16 + lm] =
                        make_ushort2(f2bf(v[nt]), f2bf(v[nt + 4]));
            } else {                                  // O=64 plain bf16
#pragma unroll
                for (int nt = 0; nt < NTN; ++nt)
                    ((ushort*)outv)[(size_t)n * 64 + nt * 16 + lm] = f2bf(v[nt]);
            }
        }
    }
}

// ---------------- host launch ----------------

extern "C" void kernel_launch(void* const* d_in, const int* in_sizes, int n_in,
                              void* d_out, int out_size, void* d_ws, size_t ws_size,
                              hipStream_t stream) {
    const float* emb = (const float*)d_in[0];
    const float* W1  = (const float*)d_in[1];
    const float* R1  = (const float*)d_in[2];
    const float* B1  = (const float*)d_in[3];
    const float* W2  = (const float*)d_in[4];
    const float* R2  = (const float*)d_in[5];
    const float* B2  = (const float*)d_in[6];
    const float* W3  = (const float*)d_in[7];
    const float* R3  = (const float*)d_in[8];
    const float* B3  = (const float*)d_in[9];
    const float* W4  = (const float*)d_in[10];
    const float* R4  = (const float*)d_in[11];
    const float* B4  = (const float*)d_in[12];
    const float* g1  = (const float*)d_in[13];
    const float* b1  = (const float*)d_in[14];
    const float* g2  = (const float*)d_in[15];
    const float* b2  = (const float*)d_in[16];
    const int*   ei  = (const int*)d_in[17];
    const int*   et  = (const int*)d_in[18];
    const int* srcp = ei;
    const int* dstp = ei + NE;

    char* ws = (char*)d_ws;
    // persistent layout (bytes):
    // segoff i32[800001]       @ 0            -> 3,200,016 (padded)
    // emeta  u64[640000]       @ 3,200,016    -> 8,320,016
    // Wp1    bf16[73728]       @ 8,320,016    -> 8,467,472
    // Wp2    bf16[147456]      @ 8,467,472    -> 8,762,384
    // Wp3    bf16[73728]       @ 8,762,384    -> 8,909,840
    // Wp4    bf16[36864]       @ 8,909,840    -> 8,983,568
    // x1     bf16-swz[NN*128]  @ 8,983,568    -> 34,583,568
    // x2     bf16-swz[NN*128]  @ 34,583,568   -> 60,183,568
    // x3     bf16[NN*64]       @ 60,183,568   -> 72,983,568
    // transients (dead before x1 written; aliased over x1 region):
    // cnt    u32[800000]       @ 8,983,568
    // cursor u32[800000]       @ 12,183,568
    // bsum   u32[512]          @ 15,383,568
    if (ws_size < 72983568u) return;
    int*      segoff = (int*)(ws + 0);
    u64*      emeta  = (u64*)(ws + 3200016);
    __bf16*   Wp1    = (__bf16*)(ws + 8320016);
    __bf16*   Wp2    = (__bf16*)(ws + 8467472);
    __bf16*   Wp3    = (__bf16*)(ws + 8762384);
    __bf16*   Wp4    = (__bf16*)(ws + 8909840);
    void*     x1     = (void*)(ws + 8983568);
    void*     x2     = (void*)(ws + 34583568);
    void*     x3     = (void*)(ws + 60183568);
    unsigned* cnt    = (unsigned*)(ws + 8983568);
    unsigned* cursor = (unsigned*)(ws + 12183568);
    unsigned* bsum   = (unsigned*)(ws + 15383568);
    float*    outp   = (float*)d_out;

    hipMemsetAsync(cnt, 0, 3200000, stream);
    hipMemsetAsync(cursor, 0, 3200000, stream);

    count_kernel<<<(NE + 255) / 256, 256, 0, stream>>>(dstp, et, cnt);
    scan1_kernel<<<NSB, 256, 0, stream>>>(cnt, bsum);
    scan2_kernel<<<1, 512, 0, stream>>>(bsum, segoff);
    scan3_kernel<<<NSB, 256, 0, stream>>>(cnt, bsum, segoff);
    fill_kernel<<<(NE + 255) / 256, 256, 0, stream>>>(
        srcp, dstp, et, segoff, cursor, cnt, emeta);

    pack_kernel<64, 128><<<(9 * 2 * 8 * 64 + 255) / 256, 256, 0, stream>>>(W1, R1, Wp1);
    pack_kernel<128, 128><<<(9 * 4 * 8 * 64 + 255) / 256, 256, 0, stream>>>(W2, R2, Wp2);
    pack_kernel<128, 64><<<(9 * 4 * 4 * 64 + 255) / 256, 256, 0, stream>>>(W3, R3, Wp3);
    pack_kernel<64, 64><<<(9 * 2 * 4 * 64 + 255) / 256, 256, 0, stream>>>(W4, R4, Wp4);

    const int GRID = (NN + 63) / 64;   // 1563
    // L1: emb f32(D=64) -> x1 swz-bf16(O=128), relu+LN
    fused_layer<64, 128, 0, 0, 1><<<GRID, 256, 0, stream>>>(
        emb, Wp1, B1, g1, b1, segoff, emeta, x1);
    // L2: x1 swz(D=128) -> x2 swz(O=128), relu+resid+LN
    fused_layer<128, 128, 1, 1, 1><<<GRID, 256, 0, stream>>>(
        x1, Wp2, B2, g2, b2, segoff, emeta, x2);
    // L3: x2 swz(D=128) -> x3 bf16(O=64), relu
    fused_layer<128, 64, 2, 1, 2><<<GRID, 256, 0, stream>>>(
        x2, Wp3, B3, nullptr, nullptr, segoff, emeta, x3);
    // L4: x3 bf16(D=64) -> out f32(O=64), plain
    fused_layer<64, 64, 3, 2, 0><<<GRID, 256, 0, stream>>>(
        x3, Wp4, B4, nullptr, nullptr, segoff, emeta, outp);
}

// Round 7
// 824.692 us; speedup vs baseline: 2.2883x; 2.2883x over previous
//
#include <hip/hip_runtime.h>
#include <math.h>

#define NN 100000
#define NR 8
#define NE 640000
#define SEGN (NN * NR)                 // 800000
#define SPB 2048                       // segments per scan block
#define NSB ((SEGN + SPB - 1) / SPB)   // 391

#define TILES 1563                     // ceil(NN/64)
#define HT1 782
#define HT2 781
#define HP1 (HT1 * 64)                 // 50048
#define HP2 (HT2 * 64)                 // 49984
#define HPF (TILES * 64)               // 100032

typedef __attribute__((ext_vector_type(8))) __bf16 bf16x8;
typedef __attribute__((ext_vector_type(4))) float  f32x4;

__device__ __forceinline__ float bf2f(unsigned short b) {
    return __uint_as_float((unsigned)b << 16);
}
__device__ __forceinline__ unsigned short f2bf(float v) {
    __bf16 b = (__bf16)v;
    return __builtin_bit_cast(unsigned short, b);
}

// ---------------- preprocessing: CSR by (rel, dst) ----------------
// seg = rel * NN + dst  -> edges of a node-range for fixed rel are CONTIGUOUS.

__global__ __launch_bounds__(256) void count_kernel(
    const int* __restrict__ dst, const int* __restrict__ et, unsigned* __restrict__ cnt) {
    int e = blockIdx.x * 256 + threadIdx.x;
    if (e < NE) atomicAdd(&cnt[(size_t)et[e] * NN + dst[e]], 1u);
}

__global__ __launch_bounds__(256) void scan1_kernel(
    const unsigned* __restrict__ cnt, unsigned* __restrict__ bsum) {
    __shared__ unsigned red[256];
    int b = blockIdx.x, t = threadIdx.x;
    int i0 = b * SPB;
    unsigned s = 0;
#pragma unroll
    for (int k = 0; k < SPB / 256; ++k) {
        int i = i0 + k * 256 + t;
        if (i < SEGN) s += cnt[i];
    }
    red[t] = s;
    __syncthreads();
    for (int off = 128; off >= 1; off >>= 1) {
        if (t < off) red[t] += red[t + off];
        __syncthreads();
    }
    if (t == 0) bsum[b] = red[0];
}

__global__ __launch_bounds__(512) void scan2_kernel(
    unsigned* __restrict__ bsum, int* __restrict__ segoff) {
    __shared__ unsigned buf[512];
    int t = threadIdx.x;
    unsigned v = (t < NSB) ? bsum[t] : 0u;
    buf[t] = v;
    __syncthreads();
    for (int off = 1; off < 512; off <<= 1) {
        unsigned w = (t >= off) ? buf[t - off] : 0u;
        __syncthreads();
        buf[t] += w;
        __syncthreads();
    }
    if (t < NSB) bsum[t] = buf[t] - v;   // exclusive block offsets
    if (t == 0) segoff[SEGN] = NE;
}

__global__ __launch_bounds__(256) void scan3_kernel(
    const unsigned* __restrict__ cnt, const unsigned* __restrict__ bsum,
    int* __restrict__ segoff) {
    __shared__ unsigned lc[SPB];
    __shared__ unsigned tsum[256];
    int b = blockIdx.x, t = threadIdx.x;
    int i0 = b * SPB;
#pragma unroll
    for (int k = 0; k < SPB / 256; ++k) {
        int i = i0 + k * 256 + t;
        lc[k * 256 + t] = (i < SEGN) ? cnt[i] : 0u;
    }
    __syncthreads();
    unsigned s = 0;
#pragma unroll
    for (int k = 0; k < 8; ++k) s += lc[t * 8 + k];
    tsum[t] = s;
    __syncthreads();
    for (int off = 1; off < 256; off <<= 1) {
        unsigned w = (t >= off) ? tsum[t - off] : 0u;
        __syncthreads();
        tsum[t] += w;
        __syncthreads();
    }
    unsigned base = bsum[b] + tsum[t] - s;
#pragma unroll
    for (int k = 0; k < 8; ++k) {
        unsigned c = lc[t * 8 + k];
        lc[t * 8 + k] = base;
        base += c;
    }
    __syncthreads();
#pragma unroll
    for (int k = 0; k < SPB / 256; ++k) {
        int i = i0 + k * 256 + t;
        if (i < SEGN) segoff[i] = (int)lc[k * 256 + t];
    }
}

__global__ __launch_bounds__(256) void fill_kernel(
    const int* __restrict__ src, const int* __restrict__ dst, const int* __restrict__ et,
    const int* __restrict__ segoff, unsigned* __restrict__ cursor, int* __restrict__ esrc) {
    int e = blockIdx.x * 256 + threadIdx.x;
    if (e >= NE) return;
    int seg = et[e] * NN + dst[e];
    int pos = segoff[seg] + (int)atomicAdd(&cursor[seg], 1u);
    esrc[pos] = src[e];
}

// ---------------- weight pack: f32 -> bf16 in MFMA B-fragment order -------
// Wp block for (r,kt,nt): 64 lanes x 8 bf16.  Lane l holds
// B[k = kt*32 + (l>>4)*8 + j][n = nt*16 + (l&15)], j=0..7.

template <int D, int O>
__global__ __launch_bounds__(256) void pack_kernel(
    const float* __restrict__ W, const float* __restrict__ Wr, __bf16* __restrict__ Wp) {
    constexpr int KT = D / 32, NTN = O / 16;
    int idx = blockIdx.x * 256 + threadIdx.x;
    if (idx >= (NR + 1) * KT * NTN * 64) return;
    int l = idx & 63;
    int rest = idx >> 6;
    int nt = rest % NTN; rest /= NTN;
    int kt = rest % KT;
    int r  = rest / KT;
    const float* srcw = (r < NR) ? (W + (size_t)r * D * O) : Wr;
    int n  = nt * 16 + (l & 15);
    int k0 = kt * 32 + (l >> 4) * 8;
    bf16x8 v;
#pragma unroll
    for (int j = 0; j < 8; ++j) v[j] = (__bf16)srcw[(size_t)(k0 + j) * O + n];
    *(bf16x8*)(Wp + (size_t)idx * 8) = v;
}

// ---------------- gather: dense agg tensor, wave per 4 segments ----------
// agg[(r*HP + i)*D + d] bf16, i in [0,HP), r in [0,9); r==8 is root copy.
// XF: 0 = f32 rows[64]   1 = bf16 pair-swizzled ushort2[64] (D=128)
//     2 = bf16 plain ushort[64] (D=64)

template <int D, int XF>
__global__ __launch_bounds__(256) void gather_kernel(
    const void* __restrict__ xin, const int* __restrict__ segoff,
    const int* __restrict__ esrc, ushort* __restrict__ agg,
    int base, int HP)
{
    int wv = threadIdx.x >> 6, ln = threadIdx.x & 63;
    int r  = blockIdx.y;
    int i0 = blockIdx.x * 16 + wv * 4;   // this wave's 4 rows (node-offsets in half)
    int n0 = base + i0;

    const float*   xf = (const float*)xin;
    const ushort*  xb = (const ushort*)xin;
    const ushort2* xs = (const ushort2*)xin;

    if (r < 8) {
        float ax[4] = {0, 0, 0, 0}, ay[4] = {0, 0, 0, 0};
        int eo[5];
#pragma unroll
        for (int k = 0; k <= 4; ++k) {
            int node = n0 + k; if (node > NN) node = NN;
            eo[k] = segoff[r * NN + node];
        }
        for (int ei = eo[0]; ei < eo[4]; ei += 4) {
            int nb = eo[4] - ei; if (nb > 4) nb = 4;
            int ss[4]; float vx[4], vy[4];
#pragma unroll
            for (int b = 0; b < 4; ++b) ss[b] = (b < nb) ? esrc[ei + b] : 0;
#pragma unroll
            for (int b = 0; b < 4; ++b) {
                if (b < nb) {
                    if constexpr (XF == 0) {
                        vx[b] = xf[(size_t)ss[b] * 64 + ln];
                    } else if constexpr (XF == 1) {
                        ushort2 w = xs[(size_t)ss[b] * 64 + ln];
                        vx[b] = bf2f(w.x); vy[b] = bf2f(w.y);
                    } else {
                        vx[b] = bf2f(xb[(size_t)ss[b] * 64 + ln]);
                    }
                }
            }
#pragma unroll
            for (int b = 0; b < 4; ++b) {
                if (b < nb) {
                    int e = ei + b;
                    int k = (e >= eo[1]) + (e >= eo[2]) + (e >= eo[3]);
#pragma unroll
                    for (int kk = 0; kk < 4; ++kk) {
                        ax[kk] += (kk == k) ? vx[b] : 0.0f;
                        if constexpr (D == 128) ay[kk] += (kk == k) ? vy[b] : 0.0f;
                    }
                }
            }
        }
#pragma unroll
        for (int k = 0; k < 4; ++k) {
            int c = eo[k + 1] - eo[k];
            float sc = (c > 0) ? 1.0f / (float)c : 0.0f;
            size_t row = ((size_t)r * HP + i0 + k) * D;
            agg[row + ln] = f2bf(ax[k] * sc);
            if constexpr (D == 128) agg[row + 64 + ln] = f2bf(ay[k] * sc);
        }
    } else {
        // r == 8: root copy (zeros for pad rows)
#pragma unroll
        for (int k = 0; k < 4; ++k) {
            int n = n0 + k;
            float v0 = 0.0f, v1 = 0.0f;
            if (n < NN) {
                if constexpr (XF == 0) {
                    v0 = xf[(size_t)n * 64 + ln];
                } else if constexpr (XF == 1) {
                    ushort2 w = xs[(size_t)n * 64 + ln];
                    v0 = bf2f(w.x); v1 = bf2f(w.y);
                } else {
                    v0 = bf2f(xb[(size_t)n * 64 + ln]);
                }
            }
            size_t row = ((size_t)8 * HP + i0 + k) * D;
            agg[row + ln] = f2bf(v0);
            if constexpr (D == 128) agg[row + 64 + ln] = f2bf(v1);
        }
    }
}

// ---------------- dense GEMM over K = 9*D, no LDS, no barriers -------------
// A-frags straight from agg (16B/lane); B from packed Wp (L1/L2-resident).
// MODE 0: relu+LN; 1: relu+resid+LN; 2: relu; 3: plain
// OF: 0 = f32 rows[O]  1 = bf16 pair-swizzled (O=128)  2 = bf16 plain (O=64)

template <int D, int O, int MODE, int OF>
__global__ __launch_bounds__(256) void gemm_layer(
    const ushort* __restrict__ agg, const __bf16* __restrict__ Wp,
    const float* __restrict__ bias, const float* __restrict__ gamma,
    const float* __restrict__ beta, void* __restrict__ outv,
    int base, int HP)
{
    constexpr int KT = D / 32, NTN = O / 16;
    int t = threadIdx.x, wv = t >> 6, ln = t & 63, lg = ln >> 4, lm = ln & 15;
    int i0 = blockIdx.x * 64;

    f32x4 acc[NTN];
#pragma unroll
    for (int nt = 0; nt < NTN; ++nt)
#pragma unroll
        for (int q = 0; q < 4; ++q) acc[nt][q] = 0.0f;

    const ushort* abase = agg + ((size_t)(i0 + wv * 16 + lm)) * D + lg * 8;

#pragma unroll 1
    for (int r = 0; r < 9; ++r) {
        const ushort* ar = abase + (size_t)r * HP * D;
        const __bf16* bp = Wp + (((size_t)(r * KT) * NTN) << 9) + (ln << 3);
#pragma unroll
        for (int kt = 0; kt < KT; ++kt) {
            bf16x8 A = *(const bf16x8*)(ar + kt * 32);
            const __bf16* bpk = bp + (((size_t)(kt * NTN)) << 9);
#pragma unroll
            for (int nt = 0; nt < NTN; ++nt) {
                bf16x8 B = *(const bf16x8*)(bpk + ((size_t)nt << 9));
                acc[nt] = __builtin_amdgcn_mfma_f32_16x16x32_bf16(A, B, acc[nt], 0, 0, 0);
            }
        }
    }

    // ---- epilogue (C/D layout: col = nt*16+lm, row = wv*16+lg*4+q) ----
    float bb[NTN], gg[NTN], be[NTN];
#pragma unroll
    for (int nt = 0; nt < NTN; ++nt) {
        bb[nt] = bias[nt * 16 + lm];
        if constexpr (MODE <= 1) {
            gg[nt] = gamma[nt * 16 + lm];
            be[nt] = beta[nt * 16 + lm];
        } else {
            gg[nt] = 0.0f; be[nt] = 0.0f;
        }
    }
    const ushort* rootbase = agg + ((size_t)8 * HP + i0) * D;
#pragma unroll
    for (int q = 0; q < 4; ++q) {
        int row = wv * 16 + lg * 4 + q;
        int n = base + i0 + row;
        float v[NTN];
#pragma unroll
        for (int nt = 0; nt < NTN; ++nt) {
            v[nt] = acc[nt][q] + bb[nt];
            if constexpr (MODE <= 2) v[nt] = fmaxf(v[nt], 0.0f);
            if constexpr (MODE == 1)
                v[nt] += bf2f(rootbase[(size_t)row * D + nt * 16 + lm]);  // residual = root tile
        }
        if constexpr (MODE <= 1) {
            float s1 = 0.0f, s2 = 0.0f;
#pragma unroll
            for (int nt = 0; nt < NTN; ++nt) { s1 += v[nt]; s2 += v[nt] * v[nt]; }
#pragma unroll
            for (int off = 1; off < 16; off <<= 1) {
                s1 += __shfl_xor(s1, off, 64);
                s2 += __shfl_xor(s2, off, 64);
            }
            float mu  = s1 * (1.0f / O);
            float var = s2 * (1.0f / O) - mu * mu;
            float rs  = rsqrtf(var + 1e-5f);
#pragma unroll
            for (int nt = 0; nt < NTN; ++nt) v[nt] = (v[nt] - mu) * rs * gg[nt] + be[nt];
        }
        if (n < NN) {
            if constexpr (OF == 0) {
#pragma unroll
                for (int nt = 0; nt < NTN; ++nt)
                    ((float*)outv)[(size_t)n * O + nt * 16 + lm] = v[nt];
            } else if constexpr (OF == 1) {          // O=128 pair-swizzled bf16
#pragma unroll
                for (int nt = 0; nt < 4; ++nt)
                    ((ushort2*)outv)[(size_t)n * 64 + nt * 16 + lm] =
                        make_ushort2(f2bf(v[nt]), f2bf(v[nt + 4]));
            } else {                                  // O=64 plain bf16
#pragma unroll
                for (int nt = 0; nt < NTN; ++nt)
                    ((ushort*)outv)[(size_t)n * 64 + nt * 16 + lm] = f2bf(v[nt]);
            }
        }
    }
}

// ---------------- host launch ----------------

extern "C" void kernel_launch(void* const* d_in, const int* in_sizes, int n_in,
                              void* d_out, int out_size, void* d_ws, size_t ws_size,
                              hipStream_t stream) {
    const float* emb = (const float*)d_in[0];
    const float* W1  = (const float*)d_in[1];
    const float* R1  = (const float*)d_in[2];
    const float* B1  = (const float*)d_in[3];
    const float* W2  = (const float*)d_in[4];
    const float* R2  = (const float*)d_in[5];
    const float* B2  = (const float*)d_in[6];
    const float* W3  = (const float*)d_in[7];
    const float* R3  = (const float*)d_in[8];
    const float* B3  = (const float*)d_in[9];
    const float* W4  = (const float*)d_in[10];
    const float* R4  = (const float*)d_in[11];
    const float* B4  = (const float*)d_in[12];
    const float* g1  = (const float*)d_in[13];
    const float* b1  = (const float*)d_in[14];
    const float* g2  = (const float*)d_in[15];
    const float* b2  = (const float*)d_in[16];
    const int*   ei  = (const int*)d_in[17];
    const int*   et  = (const int*)d_in[18];
    const int* srcp = ei;
    const int* dstp = ei + NE;

    char* ws = (char*)d_ws;
    // layout (bytes):
    // segoff i32[800001]       @ 0            -> 3,200,016 (padded)
    // esrc   i32[640000]       @ 3,200,016    -> 5,760,016
    // Wp1    bf16[73728]       @ 5,760,016    -> 5,907,472
    // Wp2    bf16[147456]      @ 5,907,472    -> 6,202,384
    // Wp3    bf16[73728]       @ 6,202,384    -> 6,349,840
    // Wp4    bf16[36864]       @ 6,349,840    -> 6,423,568
    // x1     bf16-swz[NN*128]  @ 6,423,568    -> 32,023,568
    // x2     bf16-swz[NN*128]  @ 32,023,568   -> 57,623,568
    // x3     bf16[NN*64]       @ 57,623,568   -> 70,423,568
    // agg    bf16[max 57.66M]  @ 70,423,568   -> 185,734,160
    // transients (dead before first gather; aliased over agg):
    // cnt    u32[800000]       @ 70,423,568
    // cursor u32[800000]       @ 73,623,568
    // bsum   u32[512]          @ 76,823,568
    if (ws_size < 185734160u) return;
    int*      segoff = (int*)(ws + 0);
    int*      esrc   = (int*)(ws + 3200016);
    __bf16*   Wp1    = (__bf16*)(ws + 5760016);
    __bf16*   Wp2    = (__bf16*)(ws + 5907472);
    __bf16*   Wp3    = (__bf16*)(ws + 6202384);
    __bf16*   Wp4    = (__bf16*)(ws + 6349840);
    void*     x1     = (void*)(ws + 6423568);
    void*     x2     = (void*)(ws + 32023568);
    void*     x3     = (void*)(ws + 57623568);
    ushort*   agg    = (ushort*)(ws + 70423568);
    unsigned* cnt    = (unsigned*)(ws + 70423568);
    unsigned* cursor = (unsigned*)(ws + 73623568);
    unsigned* bsum   = (unsigned*)(ws + 76823568);
    float*    outp   = (float*)d_out;

    hipMemsetAsync(cnt, 0, 3200000, stream);
    hipMemsetAsync(cursor, 0, 3200000, stream);

    count_kernel<<<(NE + 255) / 256, 256, 0, stream>>>(dstp, et, cnt);
    scan1_kernel<<<NSB, 256, 0, stream>>>(cnt, bsum);
    scan2_kernel<<<1, 512, 0, stream>>>(bsum, segoff);
    scan3_kernel<<<NSB, 256, 0, stream>>>(cnt, bsum, segoff);
    fill_kernel<<<(NE + 255) / 256, 256, 0, stream>>>(
        srcp, dstp, et, segoff, cursor, esrc);

    pack_kernel<64, 128><<<(9 * 2 * 8 * 64 + 255) / 256, 256, 0, stream>>>(W1, R1, Wp1);
    pack_kernel<128, 128><<<(9 * 4 * 8 * 64 + 255) / 256, 256, 0, stream>>>(W2, R2, Wp2);
    pack_kernel<128, 64><<<(9 * 4 * 4 * 64 + 255) / 256, 256, 0, stream>>>(W3, R3, Wp3);
    pack_kernel<64, 64><<<(9 * 2 * 4 * 64 + 255) / 256, 256, 0, stream>>>(W4, R4, Wp4);

    // ---- Layer 1: emb f32(D=64) -> x1 swz-bf16(O=128), relu+LN. Full pass. ----
    gather_kernel<64, 0><<<dim3(HPF / 16, 9), 256, 0, stream>>>(emb, segoff, esrc, agg, 0, HPF);
    gemm_layer<64, 128, 0, 1><<<TILES, 256, 0, stream>>>(agg, Wp1, B1, g1, b1, x1, 0, HPF);

    // ---- Layer 2: x1(D=128) -> x2(O=128), relu+resid+LN. Two halves. ----
    gather_kernel<128, 1><<<dim3(HP1 / 16, 9), 256, 0, stream>>>(x1, segoff, esrc, agg, 0, HP1);
    gemm_layer<128, 128, 1, 1><<<HT1, 256, 0, stream>>>(agg, Wp2, B2, g2, b2, x2, 0, HP1);
    gather_kernel<128, 1><<<dim3(HP2 / 16, 9), 256, 0, stream>>>(x1, segoff, esrc, agg, HP1, HP2);
    gemm_layer<128, 128, 1, 1><<<HT2, 256, 0, stream>>>(agg, Wp2, B2, g2, b2, x2, HP1, HP2);

    // ---- Layer 3: x2(D=128) -> x3 bf16(O=64), relu. Two halves. ----
    gather_kernel<128, 1><<<dim3(HP1 / 16, 9), 256, 0, stream>>>(x2, segoff, esrc, agg, 0, HP1);
    gemm_layer<128, 64, 2, 2><<<HT1, 256, 0, stream>>>(agg, Wp3, B3, nullptr, nullptr, x3, 0, HP1);
    gather_kernel<128, 1><<<dim3(HP2 / 16, 9), 256, 0, stream>>>(x2, segoff, esrc, agg, HP1, HP2);
    gemm_layer<128, 64, 2, 2><<<HT2, 256, 0, stream>>>(agg, Wp3, B3, nullptr, nullptr, x3, HP1, HP2);

    // ---- Layer 4: x3 bf16(D=64) -> out f32(O=64), plain. Full pass. ----
    gather_kernel<64, 2><<<dim3(HPF / 16, 9), 256, 0, stream>>>(x3, segoff, esrc, agg, 0, HPF);
    gemm_layer<64, 64, 3, 0><<<TILES, 256, 0, stream>>>(agg, Wp4, B4, nullptr, nullptr, outp, 0, HPF);
}